// Round 1
// baseline (685.469 us; speedup 1.0000x reference)
//
#include <hip/hip_runtime.h>

// CT parallel-beam pixel-driven back-projection.
// Geometry is static (mirrors the reference's baked-in constants).
#define BATCH 8
#define NVIEW 720
#define NDET  736
#define IMGH  512
#define IMGW  512

// DIMG/DDET ratio and angular step, computed in double then rounded once.
#define DANG_F ((float)(6.283185307179586 / 720.0))
#define RATIO_F ((float)(0.006641 / 0.0066))
#define UCENTER ((float)((NDET - 1) * 0.5))

// Block = 256 threads as a 64x4 pixel tile: lanes 0..63 cover 64 consecutive
// w (coalesced stores; per-view detector gather spans <= ~65 bins -> L1-hot).
__global__ __launch_bounds__(256) void backproject_kernel(
    const float* __restrict__ proj,  // [B, V, D]
    float* __restrict__ out)         // [B, H, W]
{
    __shared__ float2 cs[NVIEW];  // (cos*r, sin*r) per view

    // Build the per-view table once per block (720 sincos across 256 threads).
    for (int v = threadIdx.x; v < NVIEW; v += 256) {
        float ang = (float)v * DANG_F;
        float s, c;
        sincosf(ang, &s, &c);
        cs[v] = make_float2(c * RATIO_F, s * RATIO_F);
    }
    __syncthreads();

    const int b = blockIdx.z;
    const int w = blockIdx.x * 64 + (threadIdx.x & 63);
    const int h = blockIdx.y * 4 + (threadIdx.x >> 6);

    const float px = (float)w - (float)(IMGW - 1) * 0.5f;
    const float py = (float)(IMGH - 1) * 0.5f - (float)h;

    const float* __restrict__ sino = proj + (size_t)b * NVIEW * NDET;

    float acc = 0.0f;
    for (int v = 0; v < NVIEW; ++v) {
        const float2 t = cs[v];
        const float u  = fmaf(px, t.x, fmaf(py, t.y, UCENTER));
        const float u0 = floorf(u);
        const float fr = u - u0;
        const int i0   = (int)u0;
        const float* __restrict__ row = sino + v * NDET;

        float v0, v1;
        if (i0 >= 0 && i0 < NDET - 1) {
            // Fast path: both taps in range (always true for this geometry,
            // u in [~3.2, ~731.8]).
            v0 = row[i0];
            v1 = row[i0 + 1];
        } else {
            v0 = (i0 >= 0 && i0 < NDET) ? row[i0] : 0.0f;
            const int i1 = i0 + 1;
            v1 = (i1 >= 0 && i1 < NDET) ? row[i1] : 0.0f;
        }
        // acc += (1-fr)*v0 + fr*v1  ==  acc += v0 + fr*(v1-v0)
        acc += fmaf(fr, v1 - v0, v0);
    }

    out[((size_t)b * IMGH + h) * IMGW + w] = acc * DANG_F;
}

extern "C" void kernel_launch(void* const* d_in, const int* in_sizes, int n_in,
                              void* d_out, int out_size, void* d_ws, size_t ws_size,
                              hipStream_t stream) {
    const float* proj = (const float*)d_in[0];
    // d_in[1] = options vector; geometry is static, baked in as constants.
    float* out = (float*)d_out;

    dim3 block(256, 1, 1);
    dim3 grid(IMGW / 64, IMGH / 4, BATCH);
    backproject_kernel<<<grid, block, 0, stream>>>(proj, out);
}